// Round 1
// baseline (580.108 us; speedup 1.0000x reference)
//
#include <hip/hip_runtime.h>
#include <math.h>

#define B_ 1024
#define M_ 16384
#define D_ 512
#define C_ 100
#define L_ 50
#define NBINS 2048

// ---------------- K0: buffer label histogram + accumulator zero ----------------
__global__ void k_init(const int* __restrict__ blab, int* __restrict__ cnt_buf,
                       float* __restrict__ acc) {
    __shared__ int h[C_];
    int t = threadIdx.x;
    for (int i = t; i < C_; i += blockDim.x) h[i] = 0;
    __syncthreads();
    for (int i = t; i < M_; i += blockDim.x) atomicAdd(&h[blab[i]], 1);
    __syncthreads();
    for (int i = t; i < C_; i += blockDim.x) cnt_buf[i] = h[i];
    if (t < 8) acc[t] = 0.f;
}

// ---------------- K1: inverse L2 norms ----------------
// blocks: [0,B_) features, [B_,B_+M_) buffer, then L_ new-protos, L_ old-protos
__global__ __launch_bounds__(256) void k_norms(
    const float* __restrict__ feat, const float* __restrict__ buf,
    const float* __restrict__ protos, const float* __restrict__ oldp,
    const int* __restrict__ lc,
    float* __restrict__ inv_feat, float* __restrict__ inv_buf,
    float* __restrict__ inv_np, float* __restrict__ inv_op) {
    int b = blockIdx.x;
    const float* src; float* dst; int row;
    if (b < B_)                  { src = feat;   row = b;                 dst = &inv_feat[b]; }
    else if (b < B_ + M_)        { int j = b - B_;           src = buf;    row = j;      dst = &inv_buf[j]; }
    else if (b < B_ + M_ + L_)   { int j = b - B_ - M_;      src = protos; row = lc[j];  dst = &inv_np[j]; }
    else                         { int j = b - B_ - M_ - L_; src = oldp;   row = lc[j];  dst = &inv_op[j]; }
    const float* p = src + (size_t)row * D_;
    int t = threadIdx.x;
    float v0 = p[t], v1 = p[t + 256];
    __shared__ float red[256];
    red[t] = v0 * v0 + v1 * v1;
    __syncthreads();
    for (int s = 128; s > 0; s >>= 1) { if (t < s) red[t] += red[t + s]; __syncthreads(); }
    if (t == 0) *dst = 1.0f / fmaxf(sqrtf(red[0]), 1e-12f);
}

// ---------------- K2: fp32 tiled GEMM -> sims (clipped) ----------------
#define BM 64
#define BN 64
#define BK 16
__global__ __launch_bounds__(256) void k_gemm(
    const float* __restrict__ F, const float* __restrict__ Bf,
    const float* __restrict__ inv_f, const float* __restrict__ inv_b,
    float* __restrict__ sims) {
    __shared__ float As[BK][BM];
    __shared__ float Bs[BK][BN];
    int t = threadIdx.x;
    int tx = t & 15, ty = t >> 4;
    int row0 = blockIdx.y * BM;
    int col0 = blockIdx.x * BN;
    float c[4][4];
#pragma unroll
    for (int i = 0; i < 4; i++)
#pragma unroll
        for (int j = 0; j < 4; j++) c[i][j] = 0.f;
    int lr = t >> 2;          // 0..63: tile row for staging
    int lk = (t & 3) << 2;    // 0,4,8,12: k offset for staging
    const float* Ap = F  + (size_t)(row0 + lr) * D_ + lk;
    const float* Bp = Bf + (size_t)(col0 + lr) * D_ + lk;
    for (int k0 = 0; k0 < D_; k0 += BK) {
        float4 av = *(const float4*)(Ap + k0);
        float4 bv = *(const float4*)(Bp + k0);
        As[lk + 0][lr] = av.x; As[lk + 1][lr] = av.y; As[lk + 2][lr] = av.z; As[lk + 3][lr] = av.w;
        Bs[lk + 0][lr] = bv.x; Bs[lk + 1][lr] = bv.y; Bs[lk + 2][lr] = bv.z; Bs[lk + 3][lr] = bv.w;
        __syncthreads();
#pragma unroll
        for (int k = 0; k < BK; k++) {
            float a[4], bb2[4];
            *(float4*)a   = *(const float4*)&As[k][ty << 2];
            *(float4*)bb2 = *(const float4*)&Bs[k][tx << 2];
#pragma unroll
            for (int i = 0; i < 4; i++)
#pragma unroll
                for (int j = 0; j < 4; j++)
                    c[i][j] = fmaf(a[i], bb2[j], c[i][j]);
        }
        __syncthreads();
    }
    float fi[4], bj[4];
#pragma unroll
    for (int i = 0; i < 4; i++) fi[i] = inv_f[row0 + (ty << 2) + i] * 5.0f;  // 1/TEMP
#pragma unroll
    for (int j = 0; j < 4; j++) bj[j] = inv_b[col0 + (tx << 2) + j];
#pragma unroll
    for (int i = 0; i < 4; i++) {
        float4 o;
        o.x = fminf(fmaxf(c[i][0] * fi[i] * bj[0], -10.f), 10.f);
        o.y = fminf(fmaxf(c[i][1] * fi[i] * bj[1], -10.f), 10.f);
        o.z = fminf(fmaxf(c[i][2] * fi[i] * bj[2], -10.f), 10.f);
        o.w = fminf(fmaxf(c[i][3] * fi[i] * bj[3], -10.f), 10.f);
        *(float4*)&sims[(size_t)(row0 + (ty << 2) + i) * M_ + col0 + (tx << 2)] = o;
    }
}

// ---------------- K3: per-row histogram top-k selection ----------------
__global__ __launch_bounds__(256) void k_select(
    const float* __restrict__ sims, const int* __restrict__ labels,
    const int* __restrict__ blab, const int* __restrict__ cnt_buf,
    float* __restrict__ acc) {
    int row = blockIdx.x;
    int t = threadIdx.x;
    __shared__ int   hc[NBINS];
    __shared__ float he[NBINS];
    __shared__ float posAcc;
    __shared__ int   cCnt[256];
    __shared__ float cExp[256];
    __shared__ int   sufC[257];
    __shared__ float sufE[257];
    for (int i = t; i < NBINS; i += 256) { hc[i] = 0; he[i] = 0.f; }
    if (t == 0) posAcc = 0.f;
    __syncthreads();
    int lab = labels[row];
    const float* srow = sims + (size_t)row * M_;
    float pp = 0.f;
    for (int j = t; j < M_; j += 256) {
        float s = srow[j];
        float e = expf(s);
        if (blab[j] == lab) {
            pp += e;
        } else {
            int bin = (int)((s + 10.24f) * 100.0f);
            bin = min(max(bin, 0), NBINS - 1);
            atomicAdd(&hc[bin], 1);
            atomicAdd(&he[bin], e);
        }
    }
    atomicAdd(&posAcc, pp);
    __syncthreads();
    int cc = 0; float ce = 0.f;
#pragma unroll
    for (int i = 0; i < 8; i++) { cc += hc[t * 8 + i]; ce += he[t * 8 + i]; }
    cCnt[t] = cc; cExp[t] = ce;
    __syncthreads();
    if (t == 0) {
        int rc = 0; float re = 0.f;
        sufC[256] = 0; sufE[256] = 0.f;
        for (int i = 255; i >= 0; i--) { rc += cCnt[i]; re += cExp[i]; sufC[i] = rc; sufE[i] = re; }
        int n_pos = cnt_buf[lab];
        int n_neg = M_ - n_pos;
        int k = (int)(0.7f * (float)n_neg);   // matches fp32-mul + int-trunc of reference
        float negExp = 0.f;
        if (k > 0) {
            int tc = -1;
            for (int i = 0; i < 256; i++) {
                if (sufC[i] >= k && sufC[i + 1] < k) { tc = i; break; }
            }
            int above = sufC[tc + 1]; float aboveE = sufE[tc + 1];
            for (int b = tc * 8 + 7; b >= tc * 8; b--) {
                int c2 = hc[b];
                if (above + c2 >= k) {
                    negExp = aboveE + (float)(k - above) * (he[b] / (float)c2);
                    break;
                }
                above += c2; aboveE += he[b];
            }
        }
        float pos_exp = posAcc / (float)max(n_pos, 1);
        int valid = (k > 0 && n_pos > 0) ? 1 : 0;
        float denom = fmaxf(pos_exp + negExp, 1e-8f);
        float ratio = fminf(fmaxf(pos_exp / denom, 1e-8f), 1.0f);
        float loss = fminf(fmaxf(-logf(ratio), 0.f), 5.f);
        if (valid) { atomicAdd(&acc[0], loss); atomicAdd(&acc[1], 1.f); }
    }
}

// ---------------- K4: scores = sigmoid(F @ W + b) ----------------
__global__ __launch_bounds__(256) void k_scores(
    const float* __restrict__ F, const float* __restrict__ W,
    const float* __restrict__ bb, float* __restrict__ scores) {
    int wave = threadIdx.x >> 6, lane = threadIdx.x & 63;
    int row = blockIdx.x * 4 + wave;
    const float* p = F + (size_t)row * D_;
    float s = 0.f;
    for (int e = lane; e < D_; e += 64) s += p[e] * W[e];
    for (int off = 32; off > 0; off >>= 1) s += __shfl_down(s, off);
    if (lane == 0) scores[row] = 1.f / (1.f + expf(-(s + bb[0])));
}

// ---------------- K5: per-class boundary stats ----------------
__global__ __launch_bounds__(256) void k_class(
    const float* __restrict__ F, const int* __restrict__ labels,
    const float* __restrict__ scores, float* __restrict__ acc) {
    int c = blockIdx.x;
    int t = threadIdx.x;
    __shared__ int slab[B_];
    for (int r = t; r < B_; r += 256) slab[r] = labels[r];
    __shared__ float ssum; __shared__ int scnt;
    if (t == 0) { ssum = 0.f; scnt = 0; }
    __syncthreads();
    float s0 = 0.f, s1 = 0.f, q0 = 0.f, q1 = 0.f;
    float local_s = 0.f; int local_n = 0;
    for (int r = 0; r < B_; r++) {
        if (slab[r] == c) {
            const float* p = F + (size_t)r * D_;
            float v0 = p[t], v1 = p[t + 256];
            s0 += v0; s1 += v1; q0 += v0 * v0; q1 += v1 * v1;
            if (t == 0) { local_s += scores[r]; local_n++; }
        }
    }
    if (t == 0) { ssum = local_s; scnt = local_n; }
    __syncthreads();
    float fn = (float)scnt;
    float safe_n = fmaxf(fn, 1.f);
    float m0 = s0 / safe_n, m1 = s1 / safe_n;
    float dv = fmaxf(fn - 1.f, 1.f);
    float v0 = (q0 - fn * m0 * m0) / dv;
    float v1 = (q1 - fn * m1 * m1) / dv;
    __shared__ float red[256];
    red[t] = v0 + v1;
    __syncthreads();
    for (int s = 128; s > 0; s >>= 1) { if (t < s) red[t] += red[t + s]; __syncthreads(); }
    if (t == 0) {
        float var_mean = red[0] / 512.f;
        var_mean = fminf(fmaxf(var_mean, 1e-6f), 100.f);
        float target = 1.f / (1.f + expf(-var_mean));
        float mean_s = ssum / safe_n;
        float d = mean_s - target;
        float bl = fminf(d * d, 2.f);
        if (fn > 1.f) { atomicAdd(&acc[2], bl); atomicAdd(&acc[3], 1.f); }
    }
}

// ---------------- K6: PRD KL per row ----------------
__global__ __launch_bounds__(256) void k_prd(
    const float* __restrict__ F, const float* __restrict__ protos,
    const float* __restrict__ oldp, const int* __restrict__ lc,
    const float* __restrict__ inv_f, const float* __restrict__ inv_np,
    const float* __restrict__ inv_op, float* __restrict__ acc) {
    int row = blockIdx.x;
    int t = threadIdx.x;
    __shared__ float f[D_];
    __shared__ float so[L_], sn[L_];
    float invf = inv_f[row] * 5.0f;
    const float* p = F + (size_t)row * D_;
    f[t] = p[t]; f[t + 256] = p[t + 256];
    __syncthreads();
    int wave = t >> 6, lane = t & 63;
    for (int j = wave; j < 2 * L_; j += 4) {
        int idx = (j < L_) ? j : j - L_;
        const float* P = ((j < L_) ? oldp : protos) + (size_t)lc[idx] * D_;
        float inv = (j < L_) ? inv_op[idx] : inv_np[idx];
        float s = 0.f;
        for (int e = lane; e < D_; e += 64) s += f[e] * P[e];
        for (int off = 32; off > 0; off >>= 1) s += __shfl_down(s, off);
        if (lane == 0) {
            float v = fminf(fmaxf(s * invf * inv, -10.f), 10.f);
            if (j < L_) so[idx] = v; else sn[idx] = v;
        }
    }
    __syncthreads();
    if (t == 0) {
        float mo = -1e30f, mn = -1e30f;
        for (int i = 0; i < L_; i++) { mo = fmaxf(mo, so[i]); mn = fmaxf(mn, sn[i]); }
        float eo = 0.f, en = 0.f;
        for (int i = 0; i < L_; i++) { eo += expf(so[i] - mo); en += expf(sn[i] - mn); }
        float lo = logf(eo), ln_ = logf(en);
        float kl = 0.f;
        for (int i = 0; i < L_; i++) {
            float olp = so[i] - mo - lo;
            float nlp = sn[i] - mn - ln_;
            kl += expf(olp) * (olp - nlp);
        }
        atomicAdd(&acc[4], kl);
    }
}

// ---------------- K7: combine ----------------
__global__ void k_final(const float* __restrict__ acc, float* __restrict__ out) {
    float hard = acc[0] / fmaxf(acc[1], 1.f);
    float boundary = acc[2] / fmaxf(acc[3], 1.f);
    float kl = fminf(fmaxf(acc[4] / (float)B_, 0.f), 5.f);
    out[0] = hard + 0.1f * boundary + 0.2f * kl;
}

extern "C" void kernel_launch(void* const* d_in, const int* in_sizes, int n_in,
                              void* d_out, int out_size, void* d_ws, size_t ws_size,
                              hipStream_t stream) {
    const float* feat   = (const float*)d_in[0];
    const float* buf    = (const float*)d_in[1];
    const float* protos = (const float*)d_in[2];
    const float* oldp   = (const float*)d_in[3];
    const float* W      = (const float*)d_in[4];
    const float* bb     = (const float*)d_in[5];
    const int* labels   = (const int*)d_in[6];
    const int* blab     = (const int*)d_in[7];
    const int* lc       = (const int*)d_in[8];
    float* out = (float*)d_out;

    float* ws       = (float*)d_ws;
    float* sims     = ws;                            // B_*M_ floats = 64 MiB
    float* inv_feat = ws + (size_t)B_ * M_;          // 1024
    float* inv_buf  = inv_feat + B_;                 // 16384
    float* inv_op   = inv_buf + M_;                  // 50
    float* inv_np   = inv_op + L_;                   // 50
    float* scores   = inv_np + L_;                   // 1024
    int*   cnt_buf  = (int*)(scores + B_);           // 100 (padded to 128)
    float* acc      = (float*)(cnt_buf + 128);       // 8 accumulators

    k_init<<<1, 256, 0, stream>>>(blab, cnt_buf, acc);
    k_norms<<<B_ + M_ + 2 * L_, 256, 0, stream>>>(feat, buf, protos, oldp, lc,
                                                  inv_feat, inv_buf, inv_np, inv_op);
    dim3 g(M_ / BN, B_ / BM);
    k_gemm<<<g, 256, 0, stream>>>(feat, buf, inv_feat, inv_buf, sims);
    k_select<<<B_, 256, 0, stream>>>(sims, labels, blab, cnt_buf, acc);
    k_scores<<<B_ / 4, 256, 0, stream>>>(feat, W, bb, scores);
    k_class<<<C_, 256, 0, stream>>>(feat, labels, scores, acc);
    k_prd<<<B_, 256, 0, stream>>>(feat, protos, oldp, lc, inv_feat, inv_np, inv_op, acc);
    k_final<<<1, 1, 0, stream>>>(acc, out);
}

// Round 2
// 361.512 us; speedup vs baseline: 1.6047x; 1.6047x over previous
//
#include <hip/hip_runtime.h>
#include <hip/hip_bf16.h>
#include <math.h>

#define B_ 1024
#define M_ 16384
#define D_ 512
#define C_ 100
#define L_ 50
#define NBINS 2048

using short8  = __attribute__((ext_vector_type(8))) short;
using ushort8 = __attribute__((ext_vector_type(8))) unsigned short;
using f32x4   = __attribute__((ext_vector_type(4))) float;

__device__ inline void async16(const void* g, void* l) {
    __builtin_amdgcn_global_load_lds(
        (const __attribute__((address_space(1))) unsigned int*)g,
        (__attribute__((address_space(3))) unsigned int*)l, 16, 0, 0);
}

// ---------------- K0: buffer label histogram + accumulator zero ----------------
__global__ void k_init(const int* __restrict__ blab, int* __restrict__ cnt_buf,
                       float* __restrict__ acc) {
    __shared__ int h[C_];
    int t = threadIdx.x;
    for (int i = t; i < C_; i += blockDim.x) h[i] = 0;
    __syncthreads();
    for (int i = t; i < M_; i += blockDim.x) atomicAdd(&h[blab[i]], 1);
    __syncthreads();
    for (int i = t; i < C_; i += blockDim.x) cnt_buf[i] = h[i];
    if (t < 8) acc[t] = 0.f;
}

// ---------------- K1: norms + normalized bf16 conversion ----------------
// blocks: [0,B_) feats -> fbf + inv_feat, [B_,B_+M_) buffer -> bbf,
//         then L_ new-proto norms, L_ old-proto norms
__global__ __launch_bounds__(256) void k_prep(
    const float* __restrict__ feat, const float* __restrict__ buf,
    const float* __restrict__ protos, const float* __restrict__ oldp,
    const int* __restrict__ lc,
    __hip_bfloat16* __restrict__ fbf, __hip_bfloat16* __restrict__ bbf,
    float* __restrict__ inv_feat, float* __restrict__ inv_np,
    float* __restrict__ inv_op) {
    int b = blockIdx.x, t = threadIdx.x;
    const float* src; int row;
    __hip_bfloat16* dst = nullptr; float* ndst = nullptr;
    if (b < B_)                { src = feat;   row = b;                 dst = fbf + (size_t)b * D_; ndst = &inv_feat[b]; }
    else if (b < B_ + M_)      { int j = b - B_;           src = buf;    row = j;     dst = bbf + (size_t)j * D_; }
    else if (b < B_ + M_ + L_) { int j = b - B_ - M_;      src = protos; row = lc[j]; ndst = &inv_np[j]; }
    else                       { int j = b - B_ - M_ - L_; src = oldp;   row = lc[j]; ndst = &inv_op[j]; }
    const float* p = src + (size_t)row * D_;
    float v0 = p[t], v1 = p[t + 256];
    float ss = v0 * v0 + v1 * v1;
#pragma unroll
    for (int m = 32; m; m >>= 1) ss += __shfl_xor(ss, m);
    __shared__ float w4[4];
    if ((t & 63) == 0) w4[t >> 6] = ss;
    __syncthreads();
    float inv = 1.f / fmaxf(sqrtf(w4[0] + w4[1] + w4[2] + w4[3]), 1e-12f);
    if (dst) { dst[t] = __float2bfloat16(v0 * inv); dst[t + 256] = __float2bfloat16(v1 * inv); }
    if (ndst && t == 0) *ndst = inv;
}

// ---------------- K2: bf16 MFMA GEMM -> clipped sims (bf16) ----------------
#define TM 128
#define TN 128
#define TK 32
__global__ __launch_bounds__(256) void k_gemm(
    const __hip_bfloat16* __restrict__ A, const __hip_bfloat16* __restrict__ Bm,
    __hip_bfloat16* __restrict__ sims) {
    __shared__ unsigned short As[TM * TK];  // 8 KB
    __shared__ unsigned short Bs[TN * TK];  // 8 KB
    int t = threadIdx.x;
    int wave = t >> 6, lane = t & 63;
    int row0 = blockIdx.y * TM;
    int col0 = blockIdx.x * TN;
    // staging: chunk c (of 512): row = c>>2, kofs = (c&3)*8; thread t does c=t and c=t+256
    int c0 = t, c1 = t + 256;
    const ushort* Ag0 = (const ushort*)A + (size_t)(row0 + (c0 >> 2)) * D_ + (c0 & 3) * 8;
    const ushort* Ag1 = (const ushort*)A + (size_t)(row0 + (c1 >> 2)) * D_ + (c1 & 3) * 8;
    const ushort* Bg0 = (const ushort*)Bm + (size_t)(col0 + (c0 >> 2)) * D_ + (c0 & 3) * 8;
    const ushort* Bg1 = (const ushort*)Bm + (size_t)(col0 + (c1 >> 2)) * D_ + (c1 & 3) * 8;
    unsigned short* As0 = &As[c0 * 8]; unsigned short* As1 = &As[c1 * 8];
    unsigned short* Bs0 = &Bs[c0 * 8]; unsigned short* Bs1 = &Bs[c1 * 8];
    int wm = (wave & 1) * 64, wn = (wave >> 1) * 64;
    f32x4 acc[4][4];
#pragma unroll
    for (int i = 0; i < 4; i++)
#pragma unroll
        for (int j = 0; j < 4; j++) acc[i][j] = {0.f, 0.f, 0.f, 0.f};
    int fr = lane & 15, fk = (lane >> 4) * 8;
    for (int k0 = 0; k0 < D_; k0 += TK) {
        async16(Ag0 + k0, As0);
        async16(Ag1 + k0, As1);
        async16(Bg0 + k0, Bs0);
        async16(Bg1 + k0, Bs1);
        __syncthreads();   // drains vmcnt (global_load_lds) per gfx950 barrier semantics
        short8 af[4], bf2[4];
#pragma unroll
        for (int i = 0; i < 4; i++)
            af[i] = *(const short8*)&As[(wm + i * 16 + fr) * TK + fk];
#pragma unroll
        for (int j = 0; j < 4; j++)
            bf2[j] = *(const short8*)&Bs[(wn + j * 16 + fr) * TK + fk];
#pragma unroll
        for (int i = 0; i < 4; i++)
#pragma unroll
            for (int j = 0; j < 4; j++)
                acc[i][j] = __builtin_amdgcn_mfma_f32_16x16x32_bf16(af[i], bf2[j], acc[i][j], 0, 0, 0);
        __syncthreads();
    }
    // epilogue: C/D layout col=lane&15, row=(lane>>4)*4+reg (m89/m91 verified)
    int quad = lane >> 4, cpos = lane & 15;
#pragma unroll
    for (int i = 0; i < 4; i++) {
#pragma unroll
        for (int j = 0; j < 4; j++) {
            int gr0 = row0 + wm + i * 16 + quad * 4;
            int gc  = col0 + wn + j * 16 + cpos;
#pragma unroll
            for (int r = 0; r < 4; r++) {
                float v = fminf(fmaxf(acc[i][j][r] * 5.0f, -10.f), 10.f);  // /TEMP
                sims[(size_t)(gr0 + r) * M_ + gc] = __float2bfloat16(v);
            }
        }
    }
}

// ---------------- K3: per-row histogram top-k selection ----------------
__global__ __launch_bounds__(256) void k_select(
    const __hip_bfloat16* __restrict__ sims, const int* __restrict__ labels,
    const int* __restrict__ blab, const int* __restrict__ cnt_buf,
    float* __restrict__ acc) {
    int row = blockIdx.x;
    int t = threadIdx.x;
    __shared__ int   hc[2][NBINS];
    __shared__ float he[2][NBINS];
    __shared__ float posW[4];
    __shared__ int   cCnt[256];
    __shared__ float cExp[256];
    __shared__ int   sufC[257];
    __shared__ float sufE[257];
    int h = t >> 7;  // waves 0-1 -> hist 0, waves 2-3 -> hist 1
    for (int i = t; i < 2 * NBINS; i += 256) { ((int*)hc)[i] = 0; ((float*)he)[i] = 0.f; }
    __syncthreads();
    int lab = labels[row];
    const ushort* srow = (const ushort*)(sims + (size_t)row * M_);
    float pp = 0.f;
#pragma unroll
    for (int it = 0; it < 8; it++) {
        int base = it * 2048 + t * 8;
        ushort8 sv = *(const ushort8*)(srow + base);
        int4 l0 = *(const int4*)(blab + base);
        int4 l1 = *(const int4*)(blab + base + 4);
        int lb[8] = {l0.x, l0.y, l0.z, l0.w, l1.x, l1.y, l1.z, l1.w};
#pragma unroll
        for (int q = 0; q < 8; q++) {
            float s = __uint_as_float(((unsigned)sv[q]) << 16);
            float e = __expf(s);
            if (lb[q] == lab) {
                pp += e;
            } else {
                int bin = (int)((s + 10.24f) * 100.0f);
                bin = min(max(bin, 0), NBINS - 1);
                atomicAdd(&hc[h][bin], 1);
                atomicAdd(&he[h][bin], e);
            }
        }
    }
#pragma unroll
    for (int m = 32; m; m >>= 1) pp += __shfl_xor(pp, m);
    if ((t & 63) == 0) posW[t >> 6] = pp;
    __syncthreads();
    int cc = 0; float ce = 0.f;
#pragma unroll
    for (int i = 0; i < 8; i++) {
        int b2 = t * 8 + i;
        cc += hc[0][b2] + hc[1][b2];
        ce += he[0][b2] + he[1][b2];
    }
    cCnt[t] = cc; cExp[t] = ce;
    __syncthreads();
    if (t == 0) {
        int rc = 0; float re = 0.f;
        sufC[256] = 0; sufE[256] = 0.f;
        for (int i = 255; i >= 0; i--) { rc += cCnt[i]; re += cExp[i]; sufC[i] = rc; sufE[i] = re; }
        int n_pos = cnt_buf[lab];
        int n_neg = M_ - n_pos;
        int k = (int)(0.7f * (float)n_neg);   // fp32-mul + trunc matches reference
        float negExp = 0.f;
        if (k > 0) {
            int tc = -1;
            for (int i = 0; i < 256; i++) {
                if (sufC[i] >= k && sufC[i + 1] < k) { tc = i; break; }
            }
            int above = sufC[tc + 1]; float aboveE = sufE[tc + 1];
            for (int b = tc * 8 + 7; b >= tc * 8; b--) {
                int c2 = hc[0][b] + hc[1][b];
                if (above + c2 >= k) {
                    negExp = aboveE + (float)(k - above) * ((he[0][b] + he[1][b]) / (float)c2);
                    break;
                }
                above += c2; aboveE += he[0][b] + he[1][b];
            }
        }
        float posAcc = posW[0] + posW[1] + posW[2] + posW[3];
        float pos_exp = posAcc / (float)max(n_pos, 1);
        int valid = (k > 0 && n_pos > 0) ? 1 : 0;
        float denom = fmaxf(pos_exp + negExp, 1e-8f);
        float ratio = fminf(fmaxf(pos_exp / denom, 1e-8f), 1.0f);
        float loss = fminf(fmaxf(-logf(ratio), 0.f), 5.f);
        if (valid) { atomicAdd(&acc[0], loss); atomicAdd(&acc[1], 1.f); }
    }
}

// ---------------- K4: scores = sigmoid(F @ W + b) ----------------
__global__ __launch_bounds__(256) void k_scores(
    const float* __restrict__ F, const float* __restrict__ W,
    const float* __restrict__ bb, float* __restrict__ scores) {
    int wave = threadIdx.x >> 6, lane = threadIdx.x & 63;
    int row = blockIdx.x * 4 + wave;
    const float* p = F + (size_t)row * D_;
    float s = 0.f;
    for (int e = lane; e < D_; e += 64) s += p[e] * W[e];
#pragma unroll
    for (int off = 32; off > 0; off >>= 1) s += __shfl_down(s, off);
    if (lane == 0) scores[row] = 1.f / (1.f + __expf(-(s + bb[0])));
}

// ---------------- K5: per-class boundary stats ----------------
__global__ __launch_bounds__(256) void k_class(
    const float* __restrict__ F, const int* __restrict__ labels,
    const float* __restrict__ scores, float* __restrict__ acc) {
    int c = blockIdx.x;
    int t = threadIdx.x;
    __shared__ int slab[B_];
    for (int r = t; r < B_; r += 256) slab[r] = labels[r];
    __shared__ float ssum; __shared__ int scnt;
    if (t == 0) { ssum = 0.f; scnt = 0; }
    __syncthreads();
    float s0 = 0.f, s1 = 0.f, q0 = 0.f, q1 = 0.f;
    float local_s = 0.f; int local_n = 0;
    for (int r = 0; r < B_; r++) {
        if (slab[r] == c) {
            const float* p = F + (size_t)r * D_;
            float v0 = p[t], v1 = p[t + 256];
            s0 += v0; s1 += v1; q0 += v0 * v0; q1 += v1 * v1;
            if (t == 0) { local_s += scores[r]; local_n++; }
        }
    }
    if (t == 0) { ssum = local_s; scnt = local_n; }
    __syncthreads();
    float fn = (float)scnt;
    float safe_n = fmaxf(fn, 1.f);
    float m0 = s0 / safe_n, m1 = s1 / safe_n;
    float dv = fmaxf(fn - 1.f, 1.f);
    float v0 = (q0 - fn * m0 * m0) / dv;
    float v1 = (q1 - fn * m1 * m1) / dv;
    __shared__ float red[256];
    red[t] = v0 + v1;
    __syncthreads();
    for (int s = 128; s > 0; s >>= 1) { if (t < s) red[t] += red[t + s]; __syncthreads(); }
    if (t == 0) {
        float var_mean = red[0] / 512.f;
        var_mean = fminf(fmaxf(var_mean, 1e-6f), 100.f);
        float target = 1.f / (1.f + expf(-var_mean));
        float mean_s = ssum / safe_n;
        float d = mean_s - target;
        float bl = fminf(d * d, 2.f);
        if (fn > 1.f) { atomicAdd(&acc[2], bl); atomicAdd(&acc[3], 1.f); }
    }
}

// ---------------- K6: PRD KL per row ----------------
__global__ __launch_bounds__(256) void k_prd(
    const float* __restrict__ F, const float* __restrict__ protos,
    const float* __restrict__ oldp, const int* __restrict__ lc,
    const float* __restrict__ inv_f, const float* __restrict__ inv_np,
    const float* __restrict__ inv_op, float* __restrict__ acc) {
    int row = blockIdx.x;
    int t = threadIdx.x;
    __shared__ float f[D_];
    __shared__ float so[L_], sn[L_];
    float invf = inv_f[row] * 5.0f;
    const float* p = F + (size_t)row * D_;
    f[t] = p[t]; f[t + 256] = p[t + 256];
    __syncthreads();
    int wave = t >> 6, lane = t & 63;
    for (int j = wave; j < 2 * L_; j += 4) {
        int idx = (j < L_) ? j : j - L_;
        const float* P = ((j < L_) ? oldp : protos) + (size_t)lc[idx] * D_;
        float inv = (j < L_) ? inv_op[idx] : inv_np[idx];
        float s = 0.f;
        for (int e = lane; e < D_; e += 64) s += f[e] * P[e];
#pragma unroll
        for (int off = 32; off > 0; off >>= 1) s += __shfl_down(s, off);
        if (lane == 0) {
            float v = fminf(fmaxf(s * invf * inv, -10.f), 10.f);
            if (j < L_) so[idx] = v; else sn[idx] = v;
        }
    }
    __syncthreads();
    if (t == 0) {
        float mo = -1e30f, mn = -1e30f;
        for (int i = 0; i < L_; i++) { mo = fmaxf(mo, so[i]); mn = fmaxf(mn, sn[i]); }
        float eo = 0.f, en = 0.f;
        for (int i = 0; i < L_; i++) { eo += __expf(so[i] - mo); en += __expf(sn[i] - mn); }
        float lo = logf(eo), ln_ = logf(en);
        float kl = 0.f;
        for (int i = 0; i < L_; i++) {
            float olp = so[i] - mo - lo;
            float nlp = sn[i] - mn - ln_;
            kl += __expf(olp) * (olp - nlp);
        }
        atomicAdd(&acc[4], kl);
    }
}

// ---------------- K7: combine ----------------
__global__ void k_final(const float* __restrict__ acc, float* __restrict__ out) {
    float hard = acc[0] / fmaxf(acc[1], 1.f);
    float boundary = acc[2] / fmaxf(acc[3], 1.f);
    float kl = fminf(fmaxf(acc[4] / (float)B_, 0.f), 5.f);
    out[0] = hard + 0.1f * boundary + 0.2f * kl;
}

extern "C" void kernel_launch(void* const* d_in, const int* in_sizes, int n_in,
                              void* d_out, int out_size, void* d_ws, size_t ws_size,
                              hipStream_t stream) {
    const float* feat   = (const float*)d_in[0];
    const float* buf    = (const float*)d_in[1];
    const float* protos = (const float*)d_in[2];
    const float* oldp   = (const float*)d_in[3];
    const float* W      = (const float*)d_in[4];
    const float* bb     = (const float*)d_in[5];
    const int* labels   = (const int*)d_in[6];
    const int* blab     = (const int*)d_in[7];
    const int* lc       = (const int*)d_in[8];
    float* out = (float*)d_out;

    char* wsb = (char*)d_ws;
    __hip_bfloat16* sims = (__hip_bfloat16*)wsb;                       // 32 MiB
    __hip_bfloat16* fbf  = (__hip_bfloat16*)(wsb + 33554432);          // 1 MiB
    __hip_bfloat16* bbf  = (__hip_bfloat16*)(wsb + 33554432 + 1048576);// 16 MiB
    float* inv_feat = (float*)(wsb + 33554432 + 1048576 + 16777216);
    float* inv_np   = inv_feat + B_;
    float* inv_op   = inv_np + L_;
    float* scores   = inv_op + L_;
    int*   cnt_buf  = (int*)(scores + B_);
    float* acc      = (float*)(cnt_buf + 128);

    k_init<<<1, 256, 0, stream>>>(blab, cnt_buf, acc);
    k_prep<<<B_ + M_ + 2 * L_, 256, 0, stream>>>(feat, buf, protos, oldp, lc,
                                                 fbf, bbf, inv_feat, inv_np, inv_op);
    dim3 g(M_ / TN, B_ / TM);
    k_gemm<<<g, 256, 0, stream>>>(fbf, bbf, sims);
    k_select<<<B_, 256, 0, stream>>>(sims, labels, blab, cnt_buf, acc);
    k_scores<<<B_ / 4, 256, 0, stream>>>(feat, W, bb, scores);
    k_class<<<C_, 256, 0, stream>>>(feat, labels, scores, acc);
    k_prd<<<B_, 256, 0, stream>>>(feat, protos, oldp, lc, inv_feat, inv_np, inv_op, acc);
    k_final<<<1, 1, 0, stream>>>(acc, out);
}

// Round 3
// 279.202 us; speedup vs baseline: 2.0777x; 1.2948x over previous
//
#include <hip/hip_runtime.h>
#include <hip/hip_bf16.h>
#include <math.h>

#define B_ 1024
#define M_ 16384
#define D_ 512
#define C_ 100
#define L_ 50

using short8  = __attribute__((ext_vector_type(8))) short;
using ushort8 = __attribute__((ext_vector_type(8))) unsigned short;
using f32x4   = __attribute__((ext_vector_type(4))) float;

__device__ inline void async16(const void* g, void* l) {
    __builtin_amdgcn_global_load_lds(
        (const __attribute__((address_space(1))) unsigned int*)g,
        (__attribute__((address_space(3))) unsigned int*)l, 16, 0, 0);
}

// ---------------- K_pre: class bitmasks (transposed) + counts + scores + acc zero ----
// blocks [0,C_): build maskT[c][t] (byte q = pos-bits for elems q*2048+t*8..+7), cnt_buf[c]
// blocks [C_, C_+B_/4): scores = sigmoid(F@W+b), 4 rows per block; block C_ zeroes acc
__global__ __launch_bounds__(256) void k_pre(
    const int* __restrict__ blab, const float* __restrict__ F,
    const float* __restrict__ W, const float* __restrict__ bbias,
    unsigned long long* __restrict__ maskT, int* __restrict__ cnt_buf,
    float* __restrict__ scores, float* __restrict__ acc) {
    int b = blockIdx.x, t = threadIdx.x;
    if (b < C_) {
        unsigned long long m = 0;
#pragma unroll
        for (int q = 0; q < 8; q++) {
            int base = q * 2048 + t * 8;
            int4 l0 = *(const int4*)(blab + base);
            int4 l1 = *(const int4*)(blab + base + 4);
            unsigned by = 0;
            by |= (unsigned)(l0.x == b) << 0; by |= (unsigned)(l0.y == b) << 1;
            by |= (unsigned)(l0.z == b) << 2; by |= (unsigned)(l0.w == b) << 3;
            by |= (unsigned)(l1.x == b) << 4; by |= (unsigned)(l1.y == b) << 5;
            by |= (unsigned)(l1.z == b) << 6; by |= (unsigned)(l1.w == b) << 7;
            m |= ((unsigned long long)by) << (8 * q);
        }
        maskT[(size_t)b * 256 + t] = m;
        int c = __popcll(m);
#pragma unroll
        for (int o = 32; o; o >>= 1) c += __shfl_xor(c, o);
        __shared__ int w4[4];
        if ((t & 63) == 0) w4[t >> 6] = c;
        __syncthreads();
        if (t == 0) cnt_buf[b] = w4[0] + w4[1] + w4[2] + w4[3];
    } else {
        int bb2 = b - C_;
        if (bb2 == 0 && t < 8) acc[t] = 0.f;
        int wave = t >> 6, lane = t & 63;
        int row = bb2 * 4 + wave;
        const float* p = F + (size_t)row * D_;
        float s = 0.f;
        for (int e = lane; e < D_; e += 64) s += p[e] * W[e];
#pragma unroll
        for (int off = 32; off > 0; off >>= 1) s += __shfl_down(s, off);
        if (lane == 0) scores[row] = 1.f / (1.f + __expf(-(s + bbias[0])));
    }
}

// ---------------- K1: norms + normalized bf16 conversion ----------------
__global__ __launch_bounds__(256) void k_prep(
    const float* __restrict__ feat, const float* __restrict__ buf,
    const float* __restrict__ protos, const float* __restrict__ oldp,
    const int* __restrict__ lc,
    __hip_bfloat16* __restrict__ fbf, __hip_bfloat16* __restrict__ bbf,
    float* __restrict__ inv_feat, float* __restrict__ inv_np,
    float* __restrict__ inv_op) {
    int b = blockIdx.x, t = threadIdx.x;
    const float* src; int row;
    __hip_bfloat16* dst = nullptr; float* ndst = nullptr;
    if (b < B_)                { src = feat;   row = b;                 dst = fbf + (size_t)b * D_; ndst = &inv_feat[b]; }
    else if (b < B_ + M_)      { int j = b - B_;           src = buf;    row = j;     dst = bbf + (size_t)j * D_; }
    else if (b < B_ + M_ + L_) { int j = b - B_ - M_;      src = protos; row = lc[j]; ndst = &inv_np[j]; }
    else                       { int j = b - B_ - M_ - L_; src = oldp;   row = lc[j]; ndst = &inv_op[j]; }
    const float* p = src + (size_t)row * D_;
    float v0 = p[t], v1 = p[t + 256];
    float ss = v0 * v0 + v1 * v1;
#pragma unroll
    for (int m = 32; m; m >>= 1) ss += __shfl_xor(ss, m);
    __shared__ float w4[4];
    if ((t & 63) == 0) w4[t >> 6] = ss;
    __syncthreads();
    float inv = 1.f / fmaxf(sqrtf(w4[0] + w4[1] + w4[2] + w4[3]), 1e-12f);
    if (dst) { dst[t] = __float2bfloat16(v0 * inv); dst[t + 256] = __float2bfloat16(v1 * inv); }
    if (ndst && t == 0) *ndst = inv;
}

// ---------------- K2: bf16 MFMA GEMM -> clipped sims (bf16) ----------------
#define TM 128
#define TN 128
#define TK 32
__global__ __launch_bounds__(256) void k_gemm(
    const __hip_bfloat16* __restrict__ A, const __hip_bfloat16* __restrict__ Bm,
    __hip_bfloat16* __restrict__ sims) {
    __shared__ unsigned short As[TM * TK];
    __shared__ unsigned short Bs[TN * TK];
    int t = threadIdx.x;
    int wave = t >> 6, lane = t & 63;
    int row0 = blockIdx.y * TM;
    int col0 = blockIdx.x * TN;
    int c0 = t, c1 = t + 256;
    const ushort* Ag0 = (const ushort*)A + (size_t)(row0 + (c0 >> 2)) * D_ + (c0 & 3) * 8;
    const ushort* Ag1 = (const ushort*)A + (size_t)(row0 + (c1 >> 2)) * D_ + (c1 & 3) * 8;
    const ushort* Bg0 = (const ushort*)Bm + (size_t)(col0 + (c0 >> 2)) * D_ + (c0 & 3) * 8;
    const ushort* Bg1 = (const ushort*)Bm + (size_t)(col0 + (c1 >> 2)) * D_ + (c1 & 3) * 8;
    unsigned short* As0 = &As[c0 * 8]; unsigned short* As1 = &As[c1 * 8];
    unsigned short* Bs0 = &Bs[c0 * 8]; unsigned short* Bs1 = &Bs[c1 * 8];
    int wm = (wave & 1) * 64, wn = (wave >> 1) * 64;
    f32x4 acc[4][4];
#pragma unroll
    for (int i = 0; i < 4; i++)
#pragma unroll
        for (int j = 0; j < 4; j++) acc[i][j] = {0.f, 0.f, 0.f, 0.f};
    int fr = lane & 15, fk = (lane >> 4) * 8;
    for (int k0 = 0; k0 < D_; k0 += TK) {
        async16(Ag0 + k0, As0);
        async16(Ag1 + k0, As1);
        async16(Bg0 + k0, Bs0);
        async16(Bg1 + k0, Bs1);
        __syncthreads();
        short8 af[4], bf2[4];
#pragma unroll
        for (int i = 0; i < 4; i++)
            af[i] = *(const short8*)&As[(wm + i * 16 + fr) * TK + fk];
#pragma unroll
        for (int j = 0; j < 4; j++)
            bf2[j] = *(const short8*)&Bs[(wn + j * 16 + fr) * TK + fk];
#pragma unroll
        for (int i = 0; i < 4; i++)
#pragma unroll
            for (int j = 0; j < 4; j++)
                acc[i][j] = __builtin_amdgcn_mfma_f32_16x16x32_bf16(af[i], bf2[j], acc[i][j], 0, 0, 0);
        __syncthreads();
    }
    int quad = lane >> 4, cpos = lane & 15;
#pragma unroll
    for (int i = 0; i < 4; i++) {
#pragma unroll
        for (int j = 0; j < 4; j++) {
            int gr0 = row0 + wm + i * 16 + quad * 4;
            int gc  = col0 + wn + j * 16 + cpos;
#pragma unroll
            for (int r = 0; r < 4; r++) {
                float v = fminf(fmaxf(acc[i][j][r] * 5.0f, -10.f), 10.f);
                sims[(size_t)(gr0 + r) * M_ + gc] = __float2bfloat16(v);
            }
        }
    }
}

// ---------------- K3: per-row exact top-k via bf16-key bisection (atomic-free) ----
// key(bf16 bits) monotone ascending: neg -> ~bits, non-neg -> bits|0x8000.
// Positives get key=0 (excluded). T* = max T with count(key>=T) >= k.
// neg_exp = sum_{key>T*} e^s + (k - cnt_gt) * e^{val(T*)}  == ref's sorted-cumsum (exact on ties).
__global__ __launch_bounds__(256, 4) void k_select(
    const __hip_bfloat16* __restrict__ sims, const int* __restrict__ labels,
    const unsigned long long* __restrict__ maskT, const int* __restrict__ cnt_buf,
    float* __restrict__ acc) {
    int row = blockIdx.x;
    int t = threadIdx.x;
    int wave = t >> 6;
    int lab = labels[row];
    unsigned long long pm = maskT[(size_t)lab * 256 + t];
    const ushort* srow = (const ushort*)sims + (size_t)row * M_ + t * 8;

    unsigned keys[64];
    float pp = 0.f;
#pragma unroll
    for (int q = 0; q < 8; q++) {
        ushort8 sv = *(const ushort8*)(srow + q * 2048);
        unsigned pb = (unsigned)(pm >> (8 * q)) & 0xFFu;
#pragma unroll
        for (int b2 = 0; b2 < 8; b2++) {
            unsigned bits = (unsigned)(unsigned short)sv[b2];
            unsigned key = (bits & 0x8000u) ? (~bits & 0xFFFFu) : (bits | 0x8000u);
            if ((pb >> b2) & 1u) {
                pp += __expf(__uint_as_float(bits << 16));
                key = 0u;
            }
            keys[q * 8 + b2] = key;
        }
    }

    int n_pos = cnt_buf[lab];
    int k = (int)(0.7f * (float)(M_ - n_pos));   // fp32-mul + trunc matches reference

    __shared__ int warr[16][4];
    unsigned cur = 0;
    for (int r = 15; r >= 0; r--) {
        unsigned T = cur | (1u << r);
        int cnt = 0;
#pragma unroll
        for (int q = 0; q < 64; q++)
            cnt += __popcll(__ballot(keys[q] >= T));
        if ((t & 63) == 0) warr[15 - r][wave] = cnt;
        __syncthreads();
        int tot = warr[15 - r][0] + warr[15 - r][1] + warr[15 - r][2] + warr[15 - r][3];
        if (tot >= k) cur = T;
    }

    // final pass: strict > T*
    int cgt = 0; float sgt = 0.f;
#pragma unroll
    for (int q = 0; q < 64; q++) {
        unsigned key = keys[q];
        if (key > cur) {
            cgt++;
            unsigned bits = (key & 0x8000u) ? (key ^ 0x8000u) : (~key & 0xFFFFu);
            sgt += __expf(__uint_as_float(bits << 16));
        }
    }
#pragma unroll
    for (int o = 32; o; o >>= 1) {
        pp  += __shfl_xor(pp, o);
        sgt += __shfl_xor(sgt, o);
        cgt += __shfl_xor(cgt, o);
    }
    __shared__ float rP[4], rS[4]; __shared__ int rC[4];
    if ((t & 63) == 0) { rP[wave] = pp; rS[wave] = sgt; rC[wave] = cgt; }
    __syncthreads();
    if (t == 0) {
        float posAcc = rP[0] + rP[1] + rP[2] + rP[3];
        float sumGt  = rS[0] + rS[1] + rS[2] + rS[3];
        int   cntGt  = rC[0] + rC[1] + rC[2] + rC[3];
        float negExp = 0.f;
        if (k > 0) {
            unsigned bits = (cur & 0x8000u) ? (cur ^ 0x8000u) : (~cur & 0xFFFFu);
            float tval = __expf(__uint_as_float(bits << 16));
            negExp = sumGt + (float)(k - cntGt) * tval;
        }
        float pos_exp = posAcc / (float)max(n_pos, 1);
        int valid = (k > 0 && n_pos > 0) ? 1 : 0;
        float denom = fmaxf(pos_exp + negExp, 1e-8f);
        float ratio = fminf(fmaxf(pos_exp / denom, 1e-8f), 1.0f);
        float loss = fminf(fmaxf(-logf(ratio), 0.f), 5.f);
        if (valid) { atomicAdd(&acc[0], loss); atomicAdd(&acc[1], 1.f); }
    }
}

// ---------------- K5: per-class boundary stats ----------------
__global__ __launch_bounds__(256) void k_class(
    const float* __restrict__ F, const int* __restrict__ labels,
    const float* __restrict__ scores, float* __restrict__ acc) {
    int c = blockIdx.x;
    int t = threadIdx.x;
    __shared__ int slab[B_];
    for (int r = t; r < B_; r += 256) slab[r] = labels[r];
    __shared__ float ssum; __shared__ int scnt;
    if (t == 0) { ssum = 0.f; scnt = 0; }
    __syncthreads();
    float s0 = 0.f, s1 = 0.f, q0 = 0.f, q1 = 0.f;
    float local_s = 0.f; int local_n = 0;
    for (int r = 0; r < B_; r++) {
        if (slab[r] == c) {
            const float* p = F + (size_t)r * D_;
            float v0 = p[t], v1 = p[t + 256];
            s0 += v0; s1 += v1; q0 += v0 * v0; q1 += v1 * v1;
            if (t == 0) { local_s += scores[r]; local_n++; }
        }
    }
    if (t == 0) { ssum = local_s; scnt = local_n; }
    __syncthreads();
    float fn = (float)scnt;
    float safe_n = fmaxf(fn, 1.f);
    float m0 = s0 / safe_n, m1 = s1 / safe_n;
    float dv = fmaxf(fn - 1.f, 1.f);
    float v0 = (q0 - fn * m0 * m0) / dv;
    float v1 = (q1 - fn * m1 * m1) / dv;
    __shared__ float red[256];
    red[t] = v0 + v1;
    __syncthreads();
    for (int s = 128; s > 0; s >>= 1) { if (t < s) red[t] += red[t + s]; __syncthreads(); }
    if (t == 0) {
        float var_mean = red[0] / 512.f;
        var_mean = fminf(fmaxf(var_mean, 1e-6f), 100.f);
        float target = 1.f / (1.f + expf(-var_mean));
        float mean_s = ssum / safe_n;
        float d = mean_s - target;
        float bl = fminf(d * d, 2.f);
        if (fn > 1.f) { atomicAdd(&acc[2], bl); atomicAdd(&acc[3], 1.f); }
    }
}

// ---------------- K6: PRD KL per row ----------------
__global__ __launch_bounds__(256) void k_prd(
    const float* __restrict__ F, const float* __restrict__ protos,
    const float* __restrict__ oldp, const int* __restrict__ lc,
    const float* __restrict__ inv_f, const float* __restrict__ inv_np,
    const float* __restrict__ inv_op, float* __restrict__ acc) {
    int row = blockIdx.x;
    int t = threadIdx.x;
    __shared__ float f[D_];
    __shared__ float so[L_], sn[L_];
    float invf = inv_f[row] * 5.0f;
    const float* p = F + (size_t)row * D_;
    f[t] = p[t]; f[t + 256] = p[t + 256];
    __syncthreads();
    int wave = t >> 6, lane = t & 63;
    for (int j = wave; j < 2 * L_; j += 4) {
        int idx = (j < L_) ? j : j - L_;
        const float* P = ((j < L_) ? oldp : protos) + (size_t)lc[idx] * D_;
        float inv = (j < L_) ? inv_op[idx] : inv_np[idx];
        float s = 0.f;
        for (int e = lane; e < D_; e += 64) s += f[e] * P[e];
#pragma unroll
        for (int off = 32; off > 0; off >>= 1) s += __shfl_down(s, off);
        if (lane == 0) {
            float v = fminf(fmaxf(s * invf * inv, -10.f), 10.f);
            if (j < L_) so[idx] = v; else sn[idx] = v;
        }
    }
    __syncthreads();
    if (t == 0) {
        float mo = -1e30f, mn = -1e30f;
        for (int i = 0; i < L_; i++) { mo = fmaxf(mo, so[i]); mn = fmaxf(mn, sn[i]); }
        float eo = 0.f, en = 0.f;
        for (int i = 0; i < L_; i++) { eo += __expf(so[i] - mo); en += __expf(sn[i] - mn); }
        float lo = logf(eo), ln_ = logf(en);
        float kl = 0.f;
        for (int i = 0; i < L_; i++) {
            float olp = so[i] - mo - lo;
            float nlp = sn[i] - mn - ln_;
            kl += __expf(olp) * (olp - nlp);
        }
        atomicAdd(&acc[4], kl);
    }
}

// ---------------- K7: combine ----------------
__global__ void k_final(const float* __restrict__ acc, float* __restrict__ out) {
    float hard = acc[0] / fmaxf(acc[1], 1.f);
    float boundary = acc[2] / fmaxf(acc[3], 1.f);
    float kl = fminf(fmaxf(acc[4] / (float)B_, 0.f), 5.f);
    out[0] = hard + 0.1f * boundary + 0.2f * kl;
}

extern "C" void kernel_launch(void* const* d_in, const int* in_sizes, int n_in,
                              void* d_out, int out_size, void* d_ws, size_t ws_size,
                              hipStream_t stream) {
    const float* feat   = (const float*)d_in[0];
    const float* buf    = (const float*)d_in[1];
    const float* protos = (const float*)d_in[2];
    const float* oldp   = (const float*)d_in[3];
    const float* W      = (const float*)d_in[4];
    const float* bb     = (const float*)d_in[5];
    const int* labels   = (const int*)d_in[6];
    const int* blab     = (const int*)d_in[7];
    const int* lc       = (const int*)d_in[8];
    float* out = (float*)d_out;

    char* wsb = (char*)d_ws;
    __hip_bfloat16* sims = (__hip_bfloat16*)wsb;                        // 32 MiB
    __hip_bfloat16* fbf  = (__hip_bfloat16*)(wsb + 33554432);           // 1 MiB
    __hip_bfloat16* bbf  = (__hip_bfloat16*)(wsb + 34603008);           // 16 MiB
    unsigned long long* maskT = (unsigned long long*)(wsb + 51380224);  // 200 KiB
    float* inv_feat = (float*)(wsb + 51380224 + 204800);
    float* inv_np   = inv_feat + B_;
    float* inv_op   = inv_np + L_;
    float* scores   = inv_op + L_;
    int*   cnt_buf  = (int*)(scores + B_);
    float* acc      = (float*)(cnt_buf + 128);

    k_pre<<<C_ + B_ / 4, 256, 0, stream>>>(blab, feat, W, bb, maskT, cnt_buf, scores, acc);
    k_prep<<<B_ + M_ + 2 * L_, 256, 0, stream>>>(feat, buf, protos, oldp, lc,
                                                 fbf, bbf, inv_feat, inv_np, inv_op);
    dim3 g(M_ / TN, B_ / TM);
    k_gemm<<<g, 256, 0, stream>>>(fbf, bbf, sims);
    k_select<<<B_, 256, 0, stream>>>(sims, labels, maskT, cnt_buf, acc);
    k_class<<<C_, 256, 0, stream>>>(feat, labels, scores, acc);
    k_prd<<<B_, 256, 0, stream>>>(feat, protos, oldp, lc, inv_feat, inv_np, inv_op, acc);
    k_final<<<1, 1, 0, stream>>>(acc, out);
}